// Round 2
// baseline (497.501 us; speedup 1.0000x reference)
//
#include <hip/hip_runtime.h>

#define POOLED 7
#define PP 49
#define SCALE 0.0625f
#define WMAX 104  // max footprint extent (H=W=100) padded

// antiderivative of unit hat: Phi(u), Phi(-inf)=0, matches reference _hat_cdf
__device__ __forceinline__ float hat_cdf(float u) {
  if (u <= 0.0f) {
    float t = fminf(fmaxf(u + 1.0f, 0.0f), 1.0f);
    return 0.5f * t * t;
  } else {
    float t = fminf(fmaxf(1.0f - u, 0.0f), 1.0f);
    return 1.0f - 0.5f * t * t;
  }
}

// [B][C][S] -> [B][S][C] tiled transpose (S = H*W), coalesced both sides
__global__ __launch_bounds__(256)
void transpose_kernel(const float* __restrict__ in, float* __restrict__ out,
                      int C, int S) {
  __shared__ float tile[32][33];
  int b  = blockIdx.z;
  int s0 = blockIdx.x * 32;
  int c0 = blockIdx.y * 32;
  const float* inb = in + (size_t)b * C * S;
  float* outb      = out + (size_t)b * S * C;
  int tx = threadIdx.x, ty = threadIdx.y;
#pragma unroll
  for (int j = 0; j < 4; j++) {
    int c = c0 + ty + j * 8;
    int s = s0 + tx;
    tile[ty + j * 8][tx] = (c < C && s < S) ? inb[(size_t)c * S + s] : 0.0f;
  }
  __syncthreads();
#pragma unroll
  for (int j = 0; j < 4; j++) {
    int s = s0 + ty + j * 8;
    int c = c0 + tx;
    if (s < S && c < C) outb[(size_t)s * C + c] = tile[tx][ty + j * 8];
  }
}

// One block per (roi n, 64-channel quarter). 4 waves = 4 h-strips of the ROI
// footprint; each feature cell loaded once per block. lane = channel (coalesced).
// TR=true: feat layout [B][H][W][C]; TR=false: [B][C][H][W] (ws-too-small fallback).
template <bool TR>
__global__ __launch_bounds__(256)
void prroi_kernel(const float* __restrict__ feat, const float* __restrict__ rois,
                  float* __restrict__ out, int N, int C, int H, int W) {
  // 4 waves * 64 lanes * 49 accs = 49KB; weight arrays aliased at the front
  // (dead once the main loop finishes, before the reduction stage).
  __shared__ float s_red[4 * 64 * PP];
  float* s_wy = s_red;              // [7][WMAX]
  float* s_wx = s_red + 7 * WMAX;   // [7][WMAX]

  int blk = blockIdx.x;
  int n  = blk >> 2;
  int c0 = (blk & 3) << 6;
  int tid = threadIdx.x;
  int wave = tid >> 6;
  int lane = tid & 63;

  // uniform per-block roi geometry (broadcast loads)
  float bif = rois[n * 5 + 0];
  float x1  = rois[n * 5 + 1] * SCALE;
  float y1  = rois[n * 5 + 2] * SCALE;
  float x2  = rois[n * 5 + 3] * SCALE;
  float y2  = rois[n * 5 + 4] * SCALE;
  int bi = (int)bif;
  float bw = (x2 - x1) * (1.0f / POOLED);
  float bh = (y2 - y1) * (1.0f / POOLED);

  // full-ROI footprint (union of all bin supports, widened by 1; zeros harmless)
  int h0 = max(0, (int)floorf(y1) - 1);
  int h1 = min(H - 1, (int)ceilf(y2) + 1);
  int w0 = max(0, (int)floorf(x1) - 1);
  int w1 = min(W - 1, (int)ceilf(x2) + 1);
  int nh = h1 - h0 + 1;
  int nw = w1 - w0 + 1;

  // weights (cooperative; ~6 hat_cdf evals per thread)
  for (int i = tid; i < POOLED * nh; i += 256) {
    int p = i / nh, ih = i - p * nh;
    float lo = y1 + p * bh, hi = lo + bh;
    float j = (float)(h0 + ih);
    s_wy[p * WMAX + ih] = hat_cdf(hi - j) - hat_cdf(lo - j);
  }
  for (int i = tid; i < POOLED * nw; i += 256) {
    int q = i / nw, iw = i - q * nw;
    float lo = x1 + q * bw, hi = lo + bw;
    float j = (float)(w0 + iw);
    s_wx[q * WMAX + iw] = hat_cdf(hi - j) - hat_cdf(lo - j);
  }
  __syncthreads();

  // per-q column support (wave-uniform, lives in registers via unroll)
  int qa[POOLED], qb[POOLED];
#pragma unroll
  for (int q = 0; q < POOLED; q++) {
    float lo = x1 + q * bw, hi = lo + bw;
    qa[q] = max(0, (int)floorf(lo) - 1 - w0);
    qb[q] = min(nw - 1, (int)ceilf(hi) + 1 - w0);
  }

  // this wave's h-strip
  int rows = (nh + 3) >> 2;
  int ihA = wave * rows;
  int ihB = min(nh, ihA + rows);

  float acc[PP];
#pragma unroll
  for (int k = 0; k < PP; k++) acc[k] = 0.0f;

  int c = c0 + lane;
  const float* fb;
  if (TR) fb = feat + (size_t)bi * H * W * C + c;
  else    fb = feat + ((size_t)bi * C + c) * H * W;

  for (int ih = ihA; ih < ihB; ih++) {
    int h = h0 + ih;
    const float* rb;
    if (TR) rb = fb + (size_t)(h * W + w0) * C;
    else    rb = fb + (size_t)h * W + w0;

    float t[POOLED];
#pragma unroll
    for (int q = 0; q < POOLED; q++) t[q] = 0.0f;
#pragma unroll
    for (int q = 0; q < POOLED; q++) {
      const float* wq = s_wx + q * WMAX;
      for (int iw = qa[q]; iw <= qb[q]; iw++) {
        float f = TR ? rb[(size_t)iw * C] : rb[iw];
        t[q] = fmaf(f, wq[iw], t[q]);
      }
    }
#pragma unroll
    for (int p = 0; p < POOLED; p++) {
      float wyv = s_wy[p * WMAX + ih];
      if (wyv != 0.0f) {  // wave-uniform skip (~2 of 7 p's active per row)
#pragma unroll
        for (int q = 0; q < POOLED; q++)
          acc[p * POOLED + q] = fmaf(wyv, t[q], acc[p * POOLED + q]);
      }
    }
  }

  __syncthreads();  // weights now dead; reuse s_red for cross-wave reduction
  float* mine = s_red + (size_t)tid * PP;  // lane stride 49 floats: conflict-free (odd)
#pragma unroll
  for (int k = 0; k < PP; k++) mine[k] = acc[k];
  __syncthreads();

  float area = fmaxf(bw * bh, 0.0f);
  float inv_area = (area > 0.0f) ? 1.0f / fmaxf(area, 1e-12f) : 0.0f;

  // coalesced slab write: out[n][c0..c0+63][0..48] is 3136 contiguous floats
  float* oslab = out + ((size_t)n * C + c0) * PP;
  for (int i = tid; i < 64 * PP; i += 256) {
    float v = s_red[i] + s_red[i + 64 * PP] + s_red[i + 2 * 64 * PP] +
              s_red[i + 3 * 64 * PP];
    oslab[i] = v * inv_area;
  }
}

extern "C" void kernel_launch(void* const* d_in, const int* in_sizes, int n_in,
                              void* d_out, int out_size, void* d_ws, size_t ws_size,
                              hipStream_t stream) {
  const float* feat = (const float*)d_in[0];
  const float* rois = (const float*)d_in[1];
  float* out = (float*)d_out;

  const int B = 2, H = 100, W = 100;
  int N = in_sizes[1] / 5;
  int C = out_size / (N * PP);  // 256
  int S = H * W;

  size_t need = (size_t)B * C * S * sizeof(float);
  if (ws_size >= need) {
    float* ft = (float*)d_ws;
    dim3 tb(32, 8);
    dim3 tg((S + 31) / 32, (C + 31) / 32, B);
    transpose_kernel<<<tg, tb, 0, stream>>>(feat, ft, C, S);
    prroi_kernel<true><<<N * (C / 64), 256, 0, stream>>>(ft, rois, out, N, C, H, W);
  } else {
    prroi_kernel<false><<<N * (C / 64), 256, 0, stream>>>(feat, rois, out, N, C, H, W);
  }
}

// Round 3
// 156.020 us; speedup vs baseline: 3.1887x; 3.1887x over previous
//
#include <hip/hip_runtime.h>
#include <hip/hip_bf16.h>

#define POOLED 7
#define PP 49
#define SCALE 0.0625f
#define WMAX 104  // max w-footprint (W=100 + pad)
#define RMAX 24   // max rows per p-bin (bh<=14.2 -> support <=19)

// antiderivative of unit hat: Phi(u), Phi(-inf)=0, matches reference _hat_cdf
__device__ __forceinline__ float hat_cdf(float u) {
  if (u <= 0.0f) {
    float t = fminf(fmaxf(u + 1.0f, 0.0f), 1.0f);
    return 0.5f * t * t;
  } else {
    float t = fminf(fmaxf(1.0f - u, 0.0f), 1.0f);
    return 1.0f - 0.5f * t * t;
  }
}

// f32 [B][C][S] -> bf16 [B][S][C]  (S = H*W), coalesced both sides
__global__ __launch_bounds__(256)
void transpose_bf16_kernel(const float* __restrict__ in,
                           __hip_bfloat16* __restrict__ out, int C, int S) {
  __shared__ float tile[32][33];
  int b  = blockIdx.z;
  int s0 = blockIdx.x * 32;
  int c0 = blockIdx.y * 32;
  const float* inb = in + (size_t)b * C * S;
  __hip_bfloat16* outb = out + (size_t)b * S * C;
  int tx = threadIdx.x, ty = threadIdx.y;
#pragma unroll
  for (int j = 0; j < 4; j++) {
    int c = c0 + ty + j * 8, s = s0 + tx;
    tile[ty + j * 8][tx] = (c < C && s < S) ? inb[(size_t)c * S + s] : 0.0f;
  }
  __syncthreads();
#pragma unroll
  for (int j = 0; j < 4; j++) {
    int s = s0 + ty + j * 8, c = c0 + tx;
    if (s < S && c < C) outb[(size_t)s * C + c] = __float2bfloat16(tile[tx][ty + j * 8]);
  }
}

// One single-wave block per (roi n, bin-row p, 128-channel group g).
// Lane owns 2 adjacent channels (one u32 = 2 bf16 per cell load, 256B/wave).
// Each block reads only bin-row p's footprint rows; writes its outputs exclusively.
// TR=true: bf16 [B][H][W][C] scratch; TR=false: f32 [B][C][H][W] fallback (unused when ws fits).
template <bool TR>
__global__ __launch_bounds__(64)
void prroi_kernel(const __hip_bfloat16* __restrict__ ft,
                  const float* __restrict__ feat,
                  const float* __restrict__ rois,
                  float* __restrict__ out, int N, int C, int H, int W) {
  __shared__ __align__(16) float s_wx[POOLED * WMAX];
  __shared__ float s_wy[RMAX];

  const int G = C >> 7;           // # of 128-channel groups
  const int PG = POOLED * G;
  int bid = blockIdx.x;
  int n, p, g;
  if ((N & 7) == 0) {
    // XCD-chunked swizzle: all PG blocks of one roi land on the same XCD (bid%8).
    int x = bid & 7, s = bid >> 3;
    n = (s / PG) * 8 + x;
    int k = s % PG;
    p = k / G; g = k - p * G;
  } else {
    n = bid / PG;
    int k = bid - n * PG;
    p = k / G; g = k - p * G;
  }
  int lane = threadIdx.x;

  // uniform roi geometry (broadcast loads)
  float bif = rois[n * 5 + 0];
  float x1  = rois[n * 5 + 1] * SCALE;
  float y1  = rois[n * 5 + 2] * SCALE;
  float x2  = rois[n * 5 + 3] * SCALE;
  float y2  = rois[n * 5 + 4] * SCALE;
  int bi = (int)bif;
  float bw = (x2 - x1) * (1.0f / POOLED);
  float bh = (y2 - y1) * (1.0f / POOLED);
  float ylo = y1 + p * bh, yhi = ylo + bh;

  int w0 = max(0, (int)floorf(x1) - 1);
  int w1 = min(W - 1, (int)ceilf(x2) + 1);
  int nw = w1 - w0 + 1;
  int h0 = max(0, (int)floorf(ylo) - 1);
  int h1 = min(H - 1, (int)ceilf(yhi) + 1);
  int rows = h1 - h0 + 1;
  if (rows > RMAX) rows = RMAX;  // cannot trigger for this problem; safety only

  float area = fmaxf(bw * bh, 0.0f);
  float inv_area = (area > 0.0f) ? 1.0f / fmaxf(area, 1e-12f) : 0.0f;

  // x-weights (inv_area folded in) and this p's y-weights
  for (int i = lane; i < POOLED * nw; i += 64) {
    int q = i / nw, iw = i - q * nw;
    float lo = x1 + q * bw, hi = lo + bw;
    float j = (float)(w0 + iw);
    s_wx[q * WMAX + iw] = (hat_cdf(hi - j) - hat_cdf(lo - j)) * inv_area;
  }
  for (int i = lane; i < rows; i += 64) {
    float j = (float)(h0 + i);
    s_wy[i] = hat_cdf(yhi - j) - hat_cdf(ylo - j);
  }
  __syncthreads();

  float2 acc[POOLED];
#pragma unroll
  for (int q = 0; q < POOLED; q++) acc[q] = make_float2(0.0f, 0.0f);

  const int Ch = C >> 1;  // u32 (=2ch) per cell
  const uint32_t* fp = nullptr;
  const float* fa = nullptr;
  const float* fb2 = nullptr;
  if (TR) {
    fp = (const uint32_t*)ft + (size_t)bi * H * W * Ch + (g * 64 + lane);
  } else {
    int c = g * 128 + lane * 2;
    fa = feat + ((size_t)bi * C + c) * H * W;
    fb2 = fa + (size_t)H * W;
  }

  for (int ih = 0; ih < rows; ih++) {
    int h = h0 + ih;
    float2 t[POOLED];
#pragma unroll
    for (int q = 0; q < POOLED; q++) t[q] = make_float2(0.0f, 0.0f);

    if (TR) {
      const uint32_t* rb = fp + (size_t)(h * W + w0) * Ch;
      int iw = 0;
      for (; iw + 4 <= nw; iw += 4) {
        uint32_t u0 = rb[(size_t)(iw + 0) * Ch];
        uint32_t u1 = rb[(size_t)(iw + 1) * Ch];
        uint32_t u2 = rb[(size_t)(iw + 2) * Ch];
        uint32_t u3 = rb[(size_t)(iw + 3) * Ch];
        float a0 = __uint_as_float(u0 << 16), b0 = __uint_as_float(u0 & 0xffff0000u);
        float a1 = __uint_as_float(u1 << 16), b1 = __uint_as_float(u1 & 0xffff0000u);
        float a2 = __uint_as_float(u2 << 16), b2 = __uint_as_float(u2 & 0xffff0000u);
        float a3 = __uint_as_float(u3 << 16), b3 = __uint_as_float(u3 & 0xffff0000u);
#pragma unroll
        for (int q = 0; q < POOLED; q++) {
          const float4 w4 = *reinterpret_cast<const float4*>(&s_wx[q * WMAX + iw]);
          t[q].x = fmaf(a0, w4.x, t[q].x); t[q].y = fmaf(b0, w4.x, t[q].y);
          t[q].x = fmaf(a1, w4.y, t[q].x); t[q].y = fmaf(b1, w4.y, t[q].y);
          t[q].x = fmaf(a2, w4.z, t[q].x); t[q].y = fmaf(b2, w4.z, t[q].y);
          t[q].x = fmaf(a3, w4.w, t[q].x); t[q].y = fmaf(b3, w4.w, t[q].y);
        }
      }
      for (; iw < nw; iw++) {
        uint32_t u = rb[(size_t)iw * Ch];
        float a = __uint_as_float(u << 16), b = __uint_as_float(u & 0xffff0000u);
#pragma unroll
        for (int q = 0; q < POOLED; q++) {
          float wq = s_wx[q * WMAX + iw];
          t[q].x = fmaf(a, wq, t[q].x);
          t[q].y = fmaf(b, wq, t[q].y);
        }
      }
    } else {
      const float* ra = fa + (size_t)h * W + w0;
      const float* rb2 = fb2 + (size_t)h * W + w0;
      for (int iw = 0; iw < nw; iw++) {
        float a = ra[iw], b = rb2[iw];
#pragma unroll
        for (int q = 0; q < POOLED; q++) {
          float wq = s_wx[q * WMAX + iw];
          t[q].x = fmaf(a, wq, t[q].x);
          t[q].y = fmaf(b, wq, t[q].y);
        }
      }
    }

    float wyv = s_wy[ih];
#pragma unroll
    for (int q = 0; q < POOLED; q++) {
      acc[q].x = fmaf(wyv, t[q].x, acc[q].x);
      acc[q].y = fmaf(wyv, t[q].y, acc[q].y);
    }
  }

  // exclusive output slice: channels (c, c+1), bins (p, 0..6)
  int c = g * 128 + lane * 2;
  float* o = out + ((size_t)n * C + c) * PP + p * POOLED;
#pragma unroll
  for (int q = 0; q < POOLED; q++) {
    o[q] = acc[q].x;
    o[PP + q] = acc[q].y;
  }
}

extern "C" void kernel_launch(void* const* d_in, const int* in_sizes, int n_in,
                              void* d_out, int out_size, void* d_ws, size_t ws_size,
                              hipStream_t stream) {
  const float* feat = (const float*)d_in[0];
  const float* rois = (const float*)d_in[1];
  float* out = (float*)d_out;

  const int B = 2, H = 100, W = 100, S = H * W;
  int N = in_sizes[1] / 5;
  int C = out_size / (N * PP);  // 256
  int G = C / 128;

  size_t need = (size_t)B * S * C * sizeof(__hip_bfloat16);
  if (ws_size >= need && (C % 128) == 0) {
    __hip_bfloat16* ft = (__hip_bfloat16*)d_ws;
    dim3 tb(32, 8);
    dim3 tg((S + 31) / 32, (C + 31) / 32, B);
    transpose_bf16_kernel<<<tg, tb, 0, stream>>>(feat, ft, C, S);
    prroi_kernel<true><<<N * POOLED * G, 64, 0, stream>>>(ft, nullptr, rois, out, N, C, H, W);
  } else {
    prroi_kernel<false><<<N * POOLED * G, 64, 0, stream>>>(nullptr, feat, rois, out, N, C, H, W);
  }
}

// Round 4
// 134.587 us; speedup vs baseline: 3.6965x; 1.1592x over previous
//
#include <hip/hip_runtime.h>
#include <hip/hip_bf16.h>

#define POOLED 7
#define PP 49
#define SCALE 0.0625f
#define WMAX 104  // max w-footprint (W=100 + pad)
#define RMAX 20   // max rows per p-bin: bh<=14.2 -> support <= bh+2 <= 17

// antiderivative of unit hat: Phi(u), Phi(-inf)=0, matches reference _hat_cdf
__device__ __forceinline__ float hat_cdf(float u) {
  if (u <= 0.0f) {
    float t = fminf(fmaxf(u + 1.0f, 0.0f), 1.0f);
    return 0.5f * t * t;
  } else {
    float t = fminf(fmaxf(1.0f - u, 0.0f), 1.0f);
    return 1.0f - 0.5f * t * t;
  }
}

// f32 [B][C][S] -> bf16 [B][S][C]  (S = H*W), coalesced both sides
__global__ __launch_bounds__(256)
void transpose_bf16_kernel(const float* __restrict__ in,
                           __hip_bfloat16* __restrict__ out, int C, int S) {
  __shared__ float tile[32][33];
  int b  = blockIdx.z;
  int s0 = blockIdx.x * 32;
  int c0 = blockIdx.y * 32;
  const float* inb = in + (size_t)b * C * S;
  __hip_bfloat16* outb = out + (size_t)b * S * C;
  int tx = threadIdx.x, ty = threadIdx.y;
#pragma unroll
  for (int j = 0; j < 4; j++) {
    int c = c0 + ty + j * 8, s = s0 + tx;
    tile[ty + j * 8][tx] = (c < C && s < S) ? inb[(size_t)c * S + s] : 0.0f;
  }
  __syncthreads();
#pragma unroll
  for (int j = 0; j < 4; j++) {
    int s = s0 + ty + j * 8, c = c0 + tx;
    if (s < S && c < C) outb[(size_t)s * C + c] = __float2bfloat16(tile[tx][ty + j * 8]);
  }
}

// One 4-wave block per (roi n, bin-row p, 128-channel group g).
// The 4 waves split the bin-row's footprint rows (tail-killer for huge ROIs);
// lane owns 2 adjacent channels (u32 = 2 bf16 per cell, 256B/wave coalesced).
// Per-q tight column ranges avoid zero-weight FMAs. LDS reduce, exclusive writes.
template <bool TR>
__global__ __launch_bounds__(256)
void prroi_kernel(const __hip_bfloat16* __restrict__ ft,
                  const float* __restrict__ feat,
                  const float* __restrict__ rois,
                  float* __restrict__ out, int N, int C, int H, int W) {
  __shared__ __align__(16) float s_wx[POOLED * WMAX];
  __shared__ float s_wy[RMAX];
  __shared__ float s_red[4 * 64 * 14];  // 14336 B: [wave][lane][q*2+parity]

  const int G = C >> 7;  // # of 128-channel groups
  const int PG = POOLED * G;
  int bid = blockIdx.x;
  int n, p, g;
  if ((N & 7) == 0) {
    // XCD-chunked swizzle: all PG blocks of one roi land on the same XCD (bid%8)
    int x = bid & 7, s = bid >> 3;
    n = (s / PG) * 8 + x;
    int k = s % PG;
    p = k / G; g = k - p * G;
  } else {
    n = bid / PG;
    int k = bid - n * PG;
    p = k / G; g = k - p * G;
  }
  int tid = threadIdx.x;
  int wave = tid >> 6, lane = tid & 63;

  // uniform roi geometry (broadcast loads)
  float bif = rois[n * 5 + 0];
  float x1  = rois[n * 5 + 1] * SCALE;
  float y1  = rois[n * 5 + 2] * SCALE;
  float x2  = rois[n * 5 + 3] * SCALE;
  float y2  = rois[n * 5 + 4] * SCALE;
  int bi = (int)bif;
  float bw = (x2 - x1) * (1.0f / POOLED);
  float bh = (y2 - y1) * (1.0f / POOLED);
  float ylo = y1 + p * bh, yhi = ylo + bh;

  // tight supports: hat at j is nonzero iff lo-1 < j < hi+1; floor(lo)/ceil(hi)
  // are always inside, the next cell out is always zero-weight.
  int w0 = max(0, (int)floorf(x1));
  int w1 = min(W - 1, (int)ceilf(x2));
  int nw = w1 - w0 + 1;
  int h0 = max(0, (int)floorf(ylo));
  int h1 = min(H - 1, (int)ceilf(yhi));
  int rows = h1 - h0 + 1;
  if (rows > RMAX) rows = RMAX;  // cannot trigger here; safety only

  float area = fmaxf(bw * bh, 0.0f);
  float inv_area = (area > 0.0f) ? 1.0f / fmaxf(area, 1e-12f) : 0.0f;

  // x-weights (inv_area folded) and this p's y-weights
  for (int i = tid; i < POOLED * nw; i += 256) {
    int q = i / nw, iw = i - q * nw;
    float lo = x1 + q * bw, hi = lo + bw;
    float j = (float)(w0 + iw);
    s_wx[q * WMAX + iw] = (hat_cdf(hi - j) - hat_cdf(lo - j)) * inv_area;
  }
  for (int i = tid; i < rows; i += 256) {
    float j = (float)(h0 + i);
    s_wy[i] = hat_cdf(yhi - j) - hat_cdf(ylo - j);
  }
  __syncthreads();

  // per-q tight column ranges (wave-uniform)
  int qa[POOLED], qb[POOLED];
#pragma unroll
  for (int q = 0; q < POOLED; q++) {
    float lo = x1 + q * bw, hi = lo + bw;
    qa[q] = max(0, (int)floorf(lo) - w0);
    qb[q] = min(nw - 1, (int)ceilf(hi) - w0);
  }

  // this wave's row slice of the bin-row footprint
  int rpw = (rows + 3) >> 2;
  int ihA = wave * rpw;
  int ihB = min(rows, ihA + rpw);

  float2 acc[POOLED];
#pragma unroll
  for (int q = 0; q < POOLED; q++) acc[q] = make_float2(0.0f, 0.0f);

  const int Ch = C >> 1;  // u32 (=2ch) per cell
  const uint32_t* fp = nullptr;
  const float* fa = nullptr;
  const float* fb2 = nullptr;
  if (TR) {
    fp = (const uint32_t*)ft + (size_t)bi * H * W * Ch + (g * 64 + lane);
  } else {
    int c = g * 128 + lane * 2;
    fa = feat + ((size_t)bi * C + c) * H * W;
    fb2 = fa + (size_t)H * W;
  }

  for (int ih = ihA; ih < ihB; ih++) {
    float wyv = s_wy[ih];
    if (wyv == 0.0f) continue;  // wave-uniform
    int h = h0 + ih;
    if (TR) {
      const uint32_t* rb = fp + (size_t)(h * W + w0) * Ch;
#pragma unroll
      for (int q = 0; q < POOLED; q++) {
        float tx = 0.0f, ty = 0.0f;
        for (int iw = qa[q]; iw <= qb[q]; iw++) {
          uint32_t u = rb[(size_t)iw * Ch];
          float wq = s_wx[q * WMAX + iw];
          tx = fmaf(__uint_as_float(u << 16), wq, tx);
          ty = fmaf(__uint_as_float(u & 0xffff0000u), wq, ty);
        }
        acc[q].x = fmaf(wyv, tx, acc[q].x);
        acc[q].y = fmaf(wyv, ty, acc[q].y);
      }
    } else {
      const float* ra = fa + (size_t)h * W + w0;
      const float* rb2 = fb2 + (size_t)h * W + w0;
#pragma unroll
      for (int q = 0; q < POOLED; q++) {
        float tx = 0.0f, ty = 0.0f;
        for (int iw = qa[q]; iw <= qb[q]; iw++) {
          float wq = s_wx[q * WMAX + iw];
          tx = fmaf(ra[iw], wq, tx);
          ty = fmaf(rb2[iw], wq, ty);
        }
        acc[q].x = fmaf(wyv, tx, acc[q].x);
        acc[q].y = fmaf(wyv, ty, acc[q].y);
      }
    }
  }

  // cross-wave reduce via LDS (stride 14 floats -> 2-way bank alias = free)
  float* mine = s_red + (size_t)tid * 14;
#pragma unroll
  for (int q = 0; q < POOLED; q++) {
    mine[q * 2]     = acc[q].x;
    mine[q * 2 + 1] = acc[q].y;
  }
  __syncthreads();

  // exclusive slab write: channels g*128..+127, bins p*7..p*7+6
  float* oslab = out + ((size_t)n * C + g * 128) * PP + p * POOLED;
  for (int i = tid; i < 128 * POOLED; i += 256) {
    int cl = i / POOLED, q = i - cl * POOLED;
    int idx = (cl >> 1) * 14 + q * 2 + (cl & 1);
    float v = s_red[idx] + s_red[idx + 896] + s_red[idx + 2 * 896] +
              s_red[idx + 3 * 896];
    oslab[(size_t)cl * PP + q] = v;
  }
}

extern "C" void kernel_launch(void* const* d_in, const int* in_sizes, int n_in,
                              void* d_out, int out_size, void* d_ws, size_t ws_size,
                              hipStream_t stream) {
  const float* feat = (const float*)d_in[0];
  const float* rois = (const float*)d_in[1];
  float* out = (float*)d_out;

  const int B = 2, H = 100, W = 100, S = H * W;
  int N = in_sizes[1] / 5;
  int C = out_size / (N * PP);  // 256
  int G = C / 128;

  size_t need = (size_t)B * S * C * sizeof(__hip_bfloat16);
  if (ws_size >= need && (C % 128) == 0) {
    __hip_bfloat16* ft = (__hip_bfloat16*)d_ws;
    dim3 tb(32, 8);
    dim3 tg((S + 31) / 32, (C + 31) / 32, B);
    transpose_bf16_kernel<<<tg, tb, 0, stream>>>(feat, ft, C, S);
    prroi_kernel<true><<<N * POOLED * G, 256, 0, stream>>>(ft, nullptr, rois, out, N, C, H, W);
  } else {
    prroi_kernel<false><<<N * POOLED * G, 256, 0, stream>>>(nullptr, feat, rois, out, N, C, H, W);
  }
}

// Round 5
// 87.819 us; speedup vs baseline: 5.6651x; 1.5326x over previous
//
#include <hip/hip_runtime.h>
#include <hip/hip_bf16.h>

#define POOLED 7
#define PP 49
#define SCALE 0.0625f
#define WMAX 104  // max w-footprint (W=100 + pad)
#define RMAX 20   // max rows per p-bin: bh<=14.2 -> tight support <= 16
#define WAVES 8
#define TW (WAVES * 64)

// antiderivative of unit hat: Phi(u), Phi(-inf)=0, matches reference _hat_cdf
__device__ __forceinline__ float hat_cdf(float u) {
  if (u <= 0.0f) {
    float t = fminf(fmaxf(u + 1.0f, 0.0f), 1.0f);
    return 0.5f * t * t;
  } else {
    float t = fminf(fmaxf(1.0f - u, 0.0f), 1.0f);
    return 1.0f - 0.5f * t * t;
  }
}

__device__ __forceinline__ float bf_lo(uint32_t u) { return __uint_as_float(u << 16); }
__device__ __forceinline__ float bf_hi(uint32_t u) { return __uint_as_float(u & 0xffff0000u); }

// f32 [B][C][S] -> bf16 [B][S][C]  (S = H*W), coalesced both sides
__global__ __launch_bounds__(256)
void transpose_bf16_kernel(const float* __restrict__ in,
                           __hip_bfloat16* __restrict__ out, int C, int S) {
  __shared__ float tile[32][33];
  int b  = blockIdx.z;
  int s0 = blockIdx.x * 32;
  int c0 = blockIdx.y * 32;
  const float* inb = in + (size_t)b * C * S;
  __hip_bfloat16* outb = out + (size_t)b * S * C;
  int tx = threadIdx.x, ty = threadIdx.y;
#pragma unroll
  for (int j = 0; j < 4; j++) {
    int c = c0 + ty + j * 8, s = s0 + tx;
    tile[ty + j * 8][tx] = (c < C && s < S) ? inb[(size_t)c * S + s] : 0.0f;
  }
  __syncthreads();
#pragma unroll
  for (int j = 0; j < 4; j++) {
    int s = s0 + ty + j * 8, c = c0 + tx;
    if (s < S && c < C) outb[(size_t)s * C + c] = __float2bfloat16(tile[tx][ty + j * 8]);
  }
}

// One 8-wave block per (roi n, bin-row p, 256-channel group g).
// Lane owns 4 adjacent channels (uint2 = 4 bf16 per cell, 512B/wave coalesced).
// Waves take rows round-robin (ih = wave, wave+8, ...) -> tail-killer.
// Per-q tight column ranges; 3-stage LDS tree reduce; coalesced final write.
template <bool TR>
__global__ __launch_bounds__(TW, 2)
void prroi_kernel(const __hip_bfloat16* __restrict__ ft,
                  const float* __restrict__ feat,
                  const float* __restrict__ rois,
                  float* __restrict__ out, int N, int C, int H, int W) {
  __shared__ float s_wx[POOLED * WMAX];
  __shared__ float s_wy[RMAX];
  __shared__ float s_red[4 * 64 * 29];  // 29,696 B; stride 29 coprime w/ 32 banks

  const int G = C >> 8;  // # of 256-channel groups (1 here)
  const int PG = POOLED * G;
  int nb = gridDim.x;
  int bid = blockIdx.x;
  if ((nb & 7) == 0) {
    // chunked XCD swizzle: contiguous ROIs stay on one XCD for L2 reuse
    int cpx = nb >> 3;
    bid = (bid & 7) * cpx + (bid >> 3);
  }
  int n = bid / PG;
  int k = bid - n * PG;
  int p = k / G, g = k - p * G;

  int tid = threadIdx.x;
  int wave = tid >> 6, lane = tid & 63;

  // uniform roi geometry (broadcast loads)
  float bif = rois[n * 5 + 0];
  float x1  = rois[n * 5 + 1] * SCALE;
  float y1  = rois[n * 5 + 2] * SCALE;
  float x2  = rois[n * 5 + 3] * SCALE;
  float y2  = rois[n * 5 + 4] * SCALE;
  int bi = (int)bif;
  float bw = (x2 - x1) * (1.0f / POOLED);
  float bh = (y2 - y1) * (1.0f / POOLED);
  float ylo = y1 + p * bh, yhi = ylo + bh;

  // tight supports (next cell out is provably zero-weight)
  int w0 = max(0, (int)floorf(x1));
  int w1 = min(W - 1, (int)ceilf(x2));
  int nw = w1 - w0 + 1;
  int h0 = max(0, (int)floorf(ylo));
  int h1 = min(H - 1, (int)ceilf(yhi));
  int rows = h1 - h0 + 1;
  if (rows > RMAX) rows = RMAX;  // cannot trigger here; safety only

  float area = fmaxf(bw * bh, 0.0f);
  float inv_area = (area > 0.0f) ? 1.0f / fmaxf(area, 1e-12f) : 0.0f;

  // x-weights (inv_area folded) and this p's y-weights
  for (int i = tid; i < POOLED * nw; i += TW) {
    int q = i / nw, iw = i - q * nw;
    float lo = x1 + q * bw, hi = lo + bw;
    float j = (float)(w0 + iw);
    s_wx[q * WMAX + iw] = (hat_cdf(hi - j) - hat_cdf(lo - j)) * inv_area;
  }
  for (int i = tid; i < rows; i += TW) {
    float j = (float)(h0 + i);
    s_wy[i] = hat_cdf(yhi - j) - hat_cdf(ylo - j);
  }
  __syncthreads();

  // per-q tight column ranges (wave-uniform)
  int qa[POOLED], qb[POOLED];
#pragma unroll
  for (int q = 0; q < POOLED; q++) {
    float lo = x1 + q * bw, hi = lo + bw;
    qa[q] = max(0, (int)floorf(lo) - w0);
    qb[q] = min(nw - 1, (int)ceilf(hi) - w0);
  }

  float4 acc[POOLED];
#pragma unroll
  for (int q = 0; q < POOLED; q++) acc[q] = make_float4(0.f, 0.f, 0.f, 0.f);

  const int C4 = C >> 2;  // uint2 (=4ch) per cell
  const uint2* fp = nullptr;
  const float* f0 = nullptr;
  size_t S = (size_t)H * W;
  if (TR) {
    fp = (const uint2*)ft + (size_t)bi * S * C4 + (g * 64 + lane);
  } else {
    int c = (g * 64 + lane) * 4;
    f0 = feat + ((size_t)bi * C + c) * S;
  }

  // rows round-robin across waves
  for (int ih = wave; ih < rows; ih += WAVES) {
    float wyv = s_wy[ih];
    if (wyv == 0.0f) continue;  // wave-uniform
    int h = h0 + ih;
    if (TR) {
      const uint2* rb = fp + (size_t)(h * W + w0) * C4;
#pragma unroll
      for (int q = 0; q < POOLED; q++) {
        int a = qa[q], b = qb[q];
        float4 t0 = make_float4(0.f, 0.f, 0.f, 0.f);
        float4 t1 = make_float4(0.f, 0.f, 0.f, 0.f);
        int iw = a;
        for (; iw + 1 <= b; iw += 2) {  // 2 independent loads in flight
          uint2 u0 = rb[(size_t)iw * C4];
          uint2 u1 = rb[(size_t)(iw + 1) * C4];
          float wA = s_wx[q * WMAX + iw];
          float wB = s_wx[q * WMAX + iw + 1];
          t0.x = fmaf(bf_lo(u0.x), wA, t0.x); t0.y = fmaf(bf_hi(u0.x), wA, t0.y);
          t0.z = fmaf(bf_lo(u0.y), wA, t0.z); t0.w = fmaf(bf_hi(u0.y), wA, t0.w);
          t1.x = fmaf(bf_lo(u1.x), wB, t1.x); t1.y = fmaf(bf_hi(u1.x), wB, t1.y);
          t1.z = fmaf(bf_lo(u1.y), wB, t1.z); t1.w = fmaf(bf_hi(u1.y), wB, t1.w);
        }
        if (iw <= b) {
          uint2 u = rb[(size_t)iw * C4];
          float wA = s_wx[q * WMAX + iw];
          t0.x = fmaf(bf_lo(u.x), wA, t0.x); t0.y = fmaf(bf_hi(u.x), wA, t0.y);
          t0.z = fmaf(bf_lo(u.y), wA, t0.z); t0.w = fmaf(bf_hi(u.y), wA, t0.w);
        }
        acc[q].x = fmaf(wyv, t0.x + t1.x, acc[q].x);
        acc[q].y = fmaf(wyv, t0.y + t1.y, acc[q].y);
        acc[q].z = fmaf(wyv, t0.z + t1.z, acc[q].z);
        acc[q].w = fmaf(wyv, t0.w + t1.w, acc[q].w);
      }
    } else {
      const float* r0 = f0 + (size_t)h * W + w0;
#pragma unroll
      for (int q = 0; q < POOLED; q++) {
        float4 t0 = make_float4(0.f, 0.f, 0.f, 0.f);
        for (int iw = qa[q]; iw <= qb[q]; iw++) {
          float wq = s_wx[q * WMAX + iw];
          t0.x = fmaf(r0[iw], wq, t0.x);
          t0.y = fmaf(r0[iw + S], wq, t0.y);
          t0.z = fmaf(r0[iw + 2 * S], wq, t0.z);
          t0.w = fmaf(r0[iw + 3 * S], wq, t0.w);
        }
        acc[q].x = fmaf(wyv, t0.x, acc[q].x);
        acc[q].y = fmaf(wyv, t0.y, acc[q].y);
        acc[q].z = fmaf(wyv, t0.z, acc[q].z);
        acc[q].w = fmaf(wyv, t0.w, acc[q].w);
      }
    }
  }

  // 3-stage cross-wave tree reduce. Lane slot: 28 floats [cc][q] at stride 29.
  float* slot = s_red + ((size_t)((wave & 3) * 64 + lane)) * 29;
#define STORE28(dst) do { _Pragma("unroll") \
  for (int q = 0; q < POOLED; q++) { (dst)[0*7+q] = acc[q].x; (dst)[1*7+q] = acc[q].y; \
                                     (dst)[2*7+q] = acc[q].z; (dst)[3*7+q] = acc[q].w; } } while (0)
#define ADD28(src) do { _Pragma("unroll") \
  for (int q = 0; q < POOLED; q++) { acc[q].x += (src)[0*7+q]; acc[q].y += (src)[1*7+q]; \
                                     acc[q].z += (src)[2*7+q]; acc[q].w += (src)[3*7+q]; } } while (0)
  if (wave >= 4) STORE28(slot);
  __syncthreads();
  if (wave < 4) ADD28(slot);
  __syncthreads();
  if (wave == 2 || wave == 3) STORE28(s_red + ((size_t)((wave - 2) * 64 + lane)) * 29);
  __syncthreads();
  if (wave < 2) ADD28(s_red + ((size_t)(wave * 64 + lane)) * 29);
  __syncthreads();
  if (wave == 1) STORE28(s_red + (size_t)lane * 29);
  __syncthreads();
  if (wave == 0) {
    ADD28(s_red + (size_t)lane * 29);
    STORE28(s_red + (size_t)lane * 29);
  }
  __syncthreads();

  // coalesced-ish exclusive write: channels g*256..+255, bins p*7..p*7+6
  float* oslab = out + ((size_t)n * C + g * 256) * PP + p * POOLED;
  for (int i = tid; i < 256 * POOLED; i += TW) {
    int c = i / POOLED, q = i - c * POOLED;
    oslab[(size_t)c * PP + q] = s_red[(c >> 2) * 29 + (c & 3) * 7 + q];
  }
}

// never expected to run (C==256 in this problem); correctness safety net
__global__ void prroi_fallback(const float* __restrict__ feat,
                               const float* __restrict__ rois,
                               float* __restrict__ out, int N, int C, int H, int W) {
  int idx = blockIdx.x * blockDim.x + threadIdx.x;
  if (idx >= N * C * PP) return;
  int n = idx / (C * PP), r = idx % (C * PP);
  int c = r / PP, pq = r % PP;
  int p = pq / POOLED, q = pq % POOLED;
  float x1 = rois[n * 5 + 1] * SCALE, y1 = rois[n * 5 + 2] * SCALE;
  float x2 = rois[n * 5 + 3] * SCALE, y2 = rois[n * 5 + 4] * SCALE;
  int bi = (int)rois[n * 5 + 0];
  float bw = (x2 - x1) / POOLED, bh = (y2 - y1) / POOLED;
  float xlo = x1 + q * bw, xhi = xlo + bw;
  float ylo = y1 + p * bh, yhi = ylo + bh;
  float area = fmaxf(bw * bh, 0.0f);
  float inv_area = (area > 0.0f) ? 1.0f / fmaxf(area, 1e-12f) : 0.0f;
  const float* f = feat + ((size_t)bi * C + c) * H * W;
  float acc = 0.0f;
  int h0 = max(0, (int)floorf(ylo)), h1 = min(H - 1, (int)ceilf(yhi));
  int w0 = max(0, (int)floorf(xlo)), w1 = min(W - 1, (int)ceilf(xhi));
  for (int h = h0; h <= h1; h++) {
    float wy = hat_cdf(yhi - h) - hat_cdf(ylo - h);
    for (int w = w0; w <= w1; w++) {
      float wx = hat_cdf(xhi - w) - hat_cdf(xlo - w);
      acc += f[h * W + w] * wy * wx;
    }
  }
  out[idx] = acc * inv_area;
}

extern "C" void kernel_launch(void* const* d_in, const int* in_sizes, int n_in,
                              void* d_out, int out_size, void* d_ws, size_t ws_size,
                              hipStream_t stream) {
  const float* feat = (const float*)d_in[0];
  const float* rois = (const float*)d_in[1];
  float* out = (float*)d_out;

  const int B = 2, H = 100, W = 100, S = H * W;
  int N = in_sizes[1] / 5;
  int C = out_size / (N * PP);  // 256

  if ((C & 255) == 0) {
    int G = C >> 8;
    size_t need = (size_t)B * S * C * sizeof(__hip_bfloat16);
    if (ws_size >= need) {
      __hip_bfloat16* ft = (__hip_bfloat16*)d_ws;
      dim3 tb(32, 8);
      dim3 tg((S + 31) / 32, (C + 31) / 32, B);
      transpose_bf16_kernel<<<tg, tb, 0, stream>>>(feat, ft, C, S);
      prroi_kernel<true><<<N * POOLED * G, TW, 0, stream>>>(ft, nullptr, rois, out, N, C, H, W);
    } else {
      prroi_kernel<false><<<N * POOLED * G, TW, 0, stream>>>(nullptr, feat, rois, out, N, C, H, W);
    }
  } else {
    int total = N * C * PP;
    prroi_fallback<<<(total + 255) / 256, 256, 0, stream>>>(feat, rois, out, N, C, H, W);
  }
}